// Round 8
// baseline (303.486 us; speedup 1.0000x reference)
//
#include <hip/hip_runtime.h>

typedef short v8s __attribute__((ext_vector_type(8)));
typedef float v4f __attribute__((ext_vector_type(4)));

// problem constants
#define NCH    64
#define NHH    128
#define NWW    128
#define NOC    64
#define KSTEPS 18          // 576 / 32

// LDS slab: [6 rows][34 cols][64 ch] bf16, 128-byte row stride, rotation-swizzled
#define COLS 34
#define SLAB_BYTES (6 * COLS * 128)          // 26112
#define BBUF_OFF   SLAB_BYTES                // B triple-buffer
#define NBUF 3
#define LDSG_OFF   (SLAB_BYTES + NBUF * 8192)  // 50688
#define SMEM_BYTES (LDSG_OFF + 128)            // 50816 -> 3 blocks/CU

#define GW_STRIDE 6144

__device__ __forceinline__ unsigned short f2bf(float f) {
  unsigned int u = __float_as_uint(f);
  u += 0x7FFFu + ((u >> 16) & 1u);           // round-to-nearest-even
  return (unsigned short)(u >> 16);
}

// ---------------------------------------------------------------------------
// Pack expert weights into MFMA B-fragment-linear bf16, EXPERT-HALF pairing:
// stage gs = g*18 + sl (g=0..3) holds k-step sl for experts {g, g+4}:
// element ((((gs*2 + e01)*4 + nt)*64 + lane)*8 + j
//   = W[e = g + 4*e01][k = sl*32+(lane>>4)*8+j][n = nt*16+(lane&15)]
// with k = (kh*3+kw)*64 + c and W[e][k][n] = expert_w[e][n][c][kh][kw]
// ---------------------------------------------------------------------------
__global__ void pack_b_kernel(const float* __restrict__ ew,
                              unsigned short* __restrict__ bp) {
  int f = blockIdx.x * 256 + threadIdx.x;    // 0 .. 294911
  int j = f & 7;
  int t = f >> 3;
  int lane = t & 63;
  t >>= 6;
  int nt = t & 3;
  t >>= 2;                                   // t = gs*2 + e01, 0..143
  int e01 = t & 1;
  int gs = t >> 1;                           // 0..71
  int sl = gs % KSTEPS;
  int g = gs / KSTEPS;
  int e = g + 4 * e01;
  int k = sl * 32 + (lane >> 4) * 8 + j;
  int n = nt * 16 + (lane & 15);
  int khw = k >> 6;
  int c = k & 63;
  bp[f] = f2bf(ew[((e * NOC + n) * NCH + c) * 9 + khw]);
}

// ---------------------------------------------------------------------------
// Gating v2 (unchanged, known-good): one block per (b, ph), 512 threads.
// ---------------------------------------------------------------------------
__global__ __launch_bounds__(512) void gate_kernel(
    const float* __restrict__ x,
    const float* __restrict__ gw,
    const float* __restrict__ gb,
    float* __restrict__ gate_out) {
  __shared__ float xs[16][8][132];   // 16-ch chunk, 8 rows, 128 cols (+4 pad)
  __shared__ float wsum[8][32];      // pos-part row sums per (expert, feature)
  __shared__ float lg[16][8];        // logits [pw][e]

  const int pid = blockIdx.x;        // b*16 + ph
  const int ph = pid & 15;
  const int b = pid >> 4;
  const int tid = threadIdx.x;
  const int e = tid >> 6;            // expert = wave id
  const int lane = tid & 63;

  // positional row-sums: 256 threads cover (e2, j) = 8 x 32
  if (tid < 256) {
    int e2 = tid >> 5, j = tid & 31;
    const float* p = gw + e2 * GW_STRIDE + 4096 + j * 64;
    float s = 0.f;
#pragma unroll
    for (int g = 0; g < 16; ++g) {
      float4 v = *(const float4*)(p + g * 4);
      s += v.x + v.y + v.z + v.w;
    }
    wsum[e2][j] = s;
  }

  float acc[16];
#pragma unroll
  for (int pw = 0; pw < 16; ++pw) acc[pw] = 0.f;

  const float* xrow = x + ((size_t)(b * NCH) * NHH + ph * 8) * NWW;

  for (int cc = 0; cc < 4; ++cc) {
    __syncthreads();                 // prior chunk fully consumed
    for (int i = tid; i < 4096; i += 512) {
      int c = i >> 8;
      int py = (i >> 5) & 7;
      int w4 = i & 31;
      float4 v = *(const float4*)&xrow[(cc * 16 + c) * (NHH * NWW) + py * NWW + w4 * 4];
      *(float4*)&xs[c][py][w4 * 4] = v;
    }
    __syncthreads();
#pragma unroll
    for (int i = 0; i < 4; ++i) {
      int g = lane + 64 * i;         // 0..255 = (c:16, py:8, pxg:2)
      int pxg = g & 1;
      int py = (g >> 1) & 7;
      int c = g >> 4;
      const float4 wv = *(const float4*)&gw[e * GW_STRIDE + (cc * 16 + c) * 64 + py * 8 + pxg * 4];
      const float* xp = &xs[c][py][pxg * 4];
#pragma unroll
      for (int pw = 0; pw < 16; ++pw) {
        float4 xv = *(const float4*)(xp + pw * 8);
        acc[pw] += xv.x * wv.x + xv.y * wv.y + xv.z * wv.z + xv.w * wv.w;
      }
    }
  }

#pragma unroll
  for (int pw = 0; pw < 16; ++pw) {
    float v = acc[pw];
#pragma unroll
    for (int off = 32; off > 0; off >>= 1) v += __shfl_xor(v, off, 64);
    if (lane == 0) lg[pw][e] = v;
  }
  __syncthreads();

  if (tid < 16) {
    const int pw = tid;
    const float cy = (ph + 0.5f) / 16.0f;
    const float cx = (pw + 0.5f) / 16.0f;
    float l[8];
#pragma unroll
    for (int ee = 0; ee < 8; ++ee) l[ee] = lg[pw][ee] + gb[ee];
    for (int j = 0; j < 32; ++j) {
      float freq = (float)(1 << (j & 7)) * 3.14159265358979323846f;
      float base = (j < 16) ? cy : cx;
      float a = base * freq;
      float v = ((j >> 3) & 1) ? cosf(a) : sinf(a);
#pragma unroll
      for (int ee = 0; ee < 8; ++ee) l[ee] += v * wsum[ee][j];
    }
    float mx = -1e30f;
#pragma unroll
    for (int ee = 0; ee < 8; ++ee) mx = fmaxf(mx, l[ee]);
    float sum = 0.f;
#pragma unroll
    for (int ee = 0; ee < 8; ++ee) { l[ee] = expf(l[ee] - mx); sum += l[ee]; }
    float inv = 1.0f / sum;
#pragma unroll
    for (int ee = 0; ee < 8; ++ee)
      gate_out[(pid * 16 + pw) * 8 + ee] = l[ee] * inv;   // [b][ph][pw][e]
  }
}

// ---------------------------------------------------------------------------
// Async-stage one B stage (1 k-step x expert-pair = 8 KB) into buffer `buf`.
// Each wave DMAs its 2 KB quarter with two global_load_lds width-16 ops.
// ---------------------------------------------------------------------------
__device__ __forceinline__ void load_stage(const unsigned short* __restrict__ bp,
                                           char* smem, int gs, int buf,
                                           int wid, int lane) {
  const char* gsrc = (const char*)bp + gs * 8192 + wid * 2048 + lane * 16;
  char* ldst = smem + BBUF_OFF + buf * 8192 + wid * 2048;   // wave-uniform base
  __builtin_amdgcn_global_load_lds(
      (const __attribute__((address_space(1))) void*)gsrc,
      (__attribute__((address_space(3))) void*)ldst, 16, 0, 0);
  __builtin_amdgcn_global_load_lds(
      (const __attribute__((address_space(1))) void*)(gsrc + 1024),
      (__attribute__((address_space(3))) void*)(ldst + 1024), 16, 0, 0);
}

// ---------------------------------------------------------------------------
// Main fused kernel v7: block = 4 waves (256 thr), 4 rows x 32 cols x 64 oc.
// Wave (rp, och) = 2 rows x 32 cols x 32 oc x ALL experts (2 per stage):
// per k-step 4 A-reads (2 rows x 2 col-tiles, shared across 2 experts x 2
// n-frags) + 4 B-reads = 8 b128 for 16 MFMA = 0.5 reads/MFMA (v6 efficiency)
// with only vacc 64 + oacc 32 = 96 acc floats (v6 had 128): unified-file
// total ~156 regs -> 3 waves/SIMD -> 3 blocks/CU (v5 occupancy). No
// cross-wave reduction: each wave owns its (rows, oc) across all experts.
// Slab/swizzle/pipeline (72 x 8KB, vmcnt(2), raw barrier, prefetch-after-
// barrier) carried unchanged from v5/v6.
// ---------------------------------------------------------------------------
__global__ __launch_bounds__(256, 3) void moe_conv_kernel(
    const float* __restrict__ x,
    const float* __restrict__ eb,
    const unsigned short* __restrict__ bp,
    const float* __restrict__ gate,
    float* __restrict__ out) {
  __shared__ __align__(16) char smem[SMEM_BYTES];
  unsigned short* bbufs = (unsigned short*)(smem + BBUF_OFF);
  float* ldsg = (float*)(smem + LDSG_OFF);   // [patch 4][e 8]

  const int tid = threadIdx.x;
  const int bid = blockIdx.x;
  const int wseg = bid & 3;          // 4 column segments of 32
  const int hq = (bid >> 2) & 31;
  const int b = bid >> 7;
  const int w0 = wseg * 32;
  const int wid = tid >> 6;
  const int lane = tid & 63;
  const int quad = lane >> 4;
  const int l15 = lane & 15;
  const int rp = wid >> 1;           // row-pair (rows rp*2, rp*2+1)
  const int och = wid & 1;           // oc half (oc = och*32 .. +31)

  // kick off B stage 0 DMA immediately (overlaps slab staging)
  load_stage(bp, smem, 0, 0, wid, lane);

  // gates for this block's 4 patches
  if (tid < 32) {
    ldsg[tid] = gate[((b * 16 + (hq >> 1)) * 16 + wseg * 4 + (tid >> 3)) * 8 + (tid & 7)];
  }

  // --- stage x slab: rows hq*4-1 .. hq*4+4, cols w0-1 .. w0+32, all c ---
  // rotation swizzle: within-row byte = (cp*4 + ((srow&7)<<4)) & 127
  const int hbase = hq * 4 - 1;
  const int wbase = w0 - 1;
  for (int flat = tid; flat < 6 * 32 * COLS; flat += 256) {
    int col = flat % COLS;
    int t = flat / COLS;
    int cp = t & 31;                    // channel pair
    int r = t >> 5;                     // slab row 0..5
    int gh = hbase + r;
    int gw_ = wbase + col;
    float v0 = 0.f, v1 = 0.f;
    if (((unsigned)gh < 128u) && ((unsigned)gw_ < 128u)) {
      const float* px = x + (((b * NCH + cp * 2) * NHH + gh) * NWW + gw_);
      v0 = px[0];
      v1 = px[NHH * NWW];
    }
    unsigned int pk = (unsigned int)f2bf(v0) | ((unsigned int)f2bf(v1) << 16);
    int srow = r * COLS + col;
    int boff = ((cp * 4) + ((srow & 7) << 4)) & 127;
    *(unsigned int*)(smem + srow * 128 + boff) = pk;
  }

  // B stage 1 DMA before the slab barrier (barrier drains both)
  load_stage(bp, smem, 1, 1, wid, lane);
  __syncthreads();    // slab ready + B stages 0,1 landed (full drain, once)

  const v4f vzero = {0.f, 0.f, 0.f, 0.f};
  v4f oacc[4][2];                    // [m = r01*2+ct][j]
#pragma unroll
  for (int m = 0; m < 4; ++m) {
    oacc[m][0] = vzero;
    oacc[m][1] = vzero;
  }

  // wave/lane constants for A addressing (same derivation as v6)
  const int q16 = quad * 16;
  const int s7 = 4 * rp + l15;                       // rot seed
  const int rowb0 = ((rp * 2 + 0) * COLS + l15) * 128;
  const int rowb1 = ((rp * 2 + 1) * COLS + l15) * 128;

  for (int g = 0; g < 4; ++g) {      // stage group; experts {g, g+4}
    v4f vacc[4][2][2];               // [m][e01][j]
#pragma unroll
    for (int m = 0; m < 4; ++m)
#pragma unroll
      for (int e01 = 0; e01 < 2; ++e01) {
        vacc[m][e01][0] = vzero;
        vacc[m][e01][1] = vzero;
      }

#pragma unroll
    for (int sl = 0; sl < KSTEPS; ++sl) {
      const int gs = g * KSTEPS + sl;   // flat stage 0..71
      if (gs > 0) {
        asm volatile("s_waitcnt vmcnt(2)" ::: "memory");  // stage gs landed
        __builtin_amdgcn_s_barrier();                     // all waves agree
        __builtin_amdgcn_sched_barrier(0);
      }
      // prefetch stage gs+2 (clamped dummy at tail keeps vmcnt uniform)
      {
        int g2 = gs + 2;
        if (g2 > 71) g2 = 71;
        load_stage(bp, smem, g2, (gs + 2) % 3, wid, lane);
      }

      const unsigned short* bstage = bbufs + (gs % 3) * 4096;
      const int kh = sl / 6;
      const int kw = (sl / 2) % 3;
      const int ch = sl & 1;
      // B frags: experts {g, g+4} x n-frags {och*2, och*2+1}
      v8s bf[2][2];
#pragma unroll
      for (int e01 = 0; e01 < 2; ++e01)
#pragma unroll
        for (int j = 0; j < 2; ++j)
          bf[e01][j] = *(const v8s*)(bstage + (e01 * 4 + och * 2 + j) * 512 + lane * 8);
      const int kbyte = (kh * COLS + kw) * 128;
      __builtin_amdgcn_s_setprio(1);
#pragma unroll
      for (int r01 = 0; r01 < 2; ++r01) {
        const int rot = ((s7 + 2 * (r01 + kh) + kw) & 7) << 4;
        const int aoff = (q16 + ch * 64 + rot) & 127;
        const int rbase = (r01 ? rowb1 : rowb0) + kbyte + aoff;
#pragma unroll
        for (int ct = 0; ct < 2; ++ct) {
          const v8s a = *(const v8s*)(smem + rbase + ct * 2048);
          const int m = r01 * 2 + ct;
#pragma unroll
          for (int e01 = 0; e01 < 2; ++e01)
#pragma unroll
            for (int j = 0; j < 2; ++j)
              vacc[m][e01][j] =
                  __builtin_amdgcn_mfma_f32_16x16x32_bf16(a, bf[e01][j], vacc[m][e01][j], 0, 0, 0);
        }
      }
      __builtin_amdgcn_s_setprio(0);
    }

    // epilogue: bias + relu + gate for experts g and g+4
#pragma unroll
    for (int e01 = 0; e01 < 2; ++e01) {
      const int e = g + 4 * e01;
      float bias[2];
      bias[0] = eb[e * NOC + (och * 2 + 0) * 16 + l15];
      bias[1] = eb[e * NOC + (och * 2 + 1) * 16 + l15];
#pragma unroll
      for (int m = 0; m < 4; ++m) {
        const int ct = m & 1;
        float gv = ldsg[(ct * 2 + (quad >> 1)) * 8 + e];
#pragma unroll
        for (int j = 0; j < 2; ++j)
#pragma unroll
          for (int r = 0; r < 4; ++r) {
            float v = fmaxf(vacc[m][e01][j][r] + bias[j], 0.f);
            oacc[m][j][r] += v * gv;
          }
      }
    }
  }

  // ---- transpose through LDS (per-wave region) for full-line stores ----
  // fragment position: row_local = rp*2 + (m>>1), oc_local = j*16 + l15,
  //                    col = (m&1)*16 + quad*4 + r
  __syncthreads();                      // drains dummy prefetches + all reads
  float* tb = (float*)smem + wid * 2304;  // [row01:2][oc:32][36] floats = 9216 B
#pragma unroll
  for (int m = 0; m < 4; ++m) {
    const int r01 = m >> 1, ct = m & 1;
#pragma unroll
    for (int j = 0; j < 2; ++j)
      *(v4f*)(tb + (r01 * 32 + j * 16 + l15) * 36 + ct * 16 + quad * 4) = oacc[m][j];
  }
  // wave-private region: in-wave lgkmcnt ordering suffices, no barrier

  const int l7 = lane & 7;
  const int o8 = lane >> 3;             // 0..7
#pragma unroll
  for (int r01 = 0; r01 < 2; ++r01) {
    const int h = hq * 4 + rp * 2 + r01;
#pragma unroll
    for (int g4 = 0; g4 < 4; ++g4) {
      const int ocl = g4 * 8 + o8;                // 0..31 within oc half
      const v4f vv = *(const v4f*)(tb + (r01 * 32 + ocl) * 36 + l7 * 4);
      float* dst = out + ((b * NOC + och * 32 + ocl) * NHH + h) * NWW + w0 + l7 * 4;
      *(v4f*)dst = vv;
    }
  }
}

// ---------------------------------------------------------------------------
extern "C" void kernel_launch(void* const* d_in, const int* in_sizes, int n_in,
                              void* d_out, int out_size, void* d_ws, size_t ws_size,
                              hipStream_t stream) {
  const float* x  = (const float*)d_in[0];
  const float* ew = (const float*)d_in[1];
  const float* eb = (const float*)d_in[2];
  const float* gw = (const float*)d_in[3];
  const float* gb = (const float*)d_in[4];
  float* out = (float*)d_out;

  unsigned short* bp = (unsigned short*)d_ws;              // 294912 bf16 = 589824 B
  float* gate = (float*)((char*)d_ws + 589824);            // 4096*8 fp32 = 131072 B

  hipLaunchKernelGGL(pack_b_kernel, dim3(1152), dim3(256), 0, stream, ew, bp);
  hipLaunchKernelGGL(gate_kernel, dim3(256), dim3(512), 0, stream, x, gw, gb, gate);
  hipLaunchKernelGGL(moe_conv_kernel, dim3(2048), dim3(256), 0, stream, x, eb, bp, gate, out);
}

// Round 9
// 263.249 us; speedup vs baseline: 1.1528x; 1.1528x over previous
//
#include <hip/hip_runtime.h>

typedef short v8s __attribute__((ext_vector_type(8)));
typedef float v4f __attribute__((ext_vector_type(4)));

// problem constants
#define NCH    64
#define NHH    128
#define NWW    128
#define NOC    64
#define KSTEPS 18          // 576 / 32

// LDS slab: [6 rows][34 cols][64 ch] bf16, 128-byte row stride, rotation-swizzled
#define COLS 34
#define SLAB_BYTES (6 * COLS * 128)          // 26112
#define BBUF_OFF   SLAB_BYTES                // B triple-buffer
#define NBUF 3
#define LDSG_OFF   (SLAB_BYTES + NBUF * 8192)  // 50688
#define SMEM_BYTES (LDSG_OFF + 128)            // 50816 -> 3 blocks/CU

#define GW_STRIDE 6144

__device__ __forceinline__ unsigned short f2bf(float f) {
  unsigned int u = __float_as_uint(f);
  u += 0x7FFFu + ((u >> 16) & 1u);           // round-to-nearest-even
  return (unsigned short)(u >> 16);
}

// ---------------------------------------------------------------------------
// Pack expert weights into MFMA B-fragment-linear bf16 (round-1 layout):
// element (((e*18+s)*4+nt)*64+lane)*8+j  =  W[k = s*32+(lane>>4)*8+j][n = nt*16+(lane&15)]
// with k = (kh*3+kw)*64 + c  and W[k][n] = expert_w[e][n][c][kh][kw]
// ---------------------------------------------------------------------------
__global__ void pack_b_kernel(const float* __restrict__ ew,
                              unsigned short* __restrict__ bp) {
  int f = blockIdx.x * 256 + threadIdx.x;    // 0 .. 294911
  int j = f & 7;
  int t = f >> 3;
  int lane = t & 63;
  t >>= 6;
  int nt = t & 3;
  t >>= 2;                                   // t = e*18 + s, 0..143
  int s = t % KSTEPS;
  int e = t / KSTEPS;
  int k = s * 32 + (lane >> 4) * 8 + j;
  int n = nt * 16 + (lane & 15);
  int khw = k >> 6;
  int c = k & 63;
  bp[f] = f2bf(ew[((e * NOC + n) * NCH + c) * 9 + khw]);
}

// ---------------------------------------------------------------------------
// Gating v2 (unchanged, known-good): one block per (b, ph), 512 threads.
// ---------------------------------------------------------------------------
__global__ __launch_bounds__(512) void gate_kernel(
    const float* __restrict__ x,
    const float* __restrict__ gw,
    const float* __restrict__ gb,
    float* __restrict__ gate_out) {
  __shared__ float xs[16][8][132];   // 16-ch chunk, 8 rows, 128 cols (+4 pad)
  __shared__ float wsum[8][32];      // pos-part row sums per (expert, feature)
  __shared__ float lg[16][8];        // logits [pw][e]

  const int pid = blockIdx.x;        // b*16 + ph
  const int ph = pid & 15;
  const int b = pid >> 4;
  const int tid = threadIdx.x;
  const int e = tid >> 6;            // expert = wave id
  const int lane = tid & 63;

  // positional row-sums: 256 threads cover (e2, j) = 8 x 32
  if (tid < 256) {
    int e2 = tid >> 5, j = tid & 31;
    const float* p = gw + e2 * GW_STRIDE + 4096 + j * 64;
    float s = 0.f;
#pragma unroll
    for (int g = 0; g < 16; ++g) {
      float4 v = *(const float4*)(p + g * 4);
      s += v.x + v.y + v.z + v.w;
    }
    wsum[e2][j] = s;
  }

  float acc[16];
#pragma unroll
  for (int pw = 0; pw < 16; ++pw) acc[pw] = 0.f;

  const float* xrow = x + ((size_t)(b * NCH) * NHH + ph * 8) * NWW;

  for (int cc = 0; cc < 4; ++cc) {
    __syncthreads();                 // prior chunk fully consumed
    for (int i = tid; i < 4096; i += 512) {
      int c = i >> 8;
      int py = (i >> 5) & 7;
      int w4 = i & 31;
      float4 v = *(const float4*)&xrow[(cc * 16 + c) * (NHH * NWW) + py * NWW + w4 * 4];
      *(float4*)&xs[c][py][w4 * 4] = v;
    }
    __syncthreads();
#pragma unroll
    for (int i = 0; i < 4; ++i) {
      int g = lane + 64 * i;         // 0..255 = (c:16, py:8, pxg:2)
      int pxg = g & 1;
      int py = (g >> 1) & 7;
      int c = g >> 4;
      const float4 wv = *(const float4*)&gw[e * GW_STRIDE + (cc * 16 + c) * 64 + py * 8 + pxg * 4];
      const float* xp = &xs[c][py][pxg * 4];
#pragma unroll
      for (int pw = 0; pw < 16; ++pw) {
        float4 xv = *(const float4*)(xp + pw * 8);
        acc[pw] += xv.x * wv.x + xv.y * wv.y + xv.z * wv.z + xv.w * wv.w;
      }
    }
  }

#pragma unroll
  for (int pw = 0; pw < 16; ++pw) {
    float v = acc[pw];
#pragma unroll
    for (int off = 32; off > 0; off >>= 1) v += __shfl_xor(v, off, 64);
    if (lane == 0) lg[pw][e] = v;
  }
  __syncthreads();

  if (tid < 16) {
    const int pw = tid;
    const float cy = (ph + 0.5f) / 16.0f;
    const float cx = (pw + 0.5f) / 16.0f;
    float l[8];
#pragma unroll
    for (int ee = 0; ee < 8; ++ee) l[ee] = lg[pw][ee] + gb[ee];
    for (int j = 0; j < 32; ++j) {
      float freq = (float)(1 << (j & 7)) * 3.14159265358979323846f;
      float base = (j < 16) ? cy : cx;
      float a = base * freq;
      float v = ((j >> 3) & 1) ? cosf(a) : sinf(a);
#pragma unroll
      for (int ee = 0; ee < 8; ++ee) l[ee] += v * wsum[ee][j];
    }
    float mx = -1e30f;
#pragma unroll
    for (int ee = 0; ee < 8; ++ee) mx = fmaxf(mx, l[ee]);
    float sum = 0.f;
#pragma unroll
    for (int ee = 0; ee < 8; ++ee) { l[ee] = expf(l[ee] - mx); sum += l[ee]; }
    float inv = 1.0f / sum;
#pragma unroll
    for (int ee = 0; ee < 8; ++ee)
      gate_out[(pid * 16 + pw) * 8 + ee] = l[ee] * inv;   // [b][ph][pw][e]
  }
}

// ---------------------------------------------------------------------------
// Async-stage one B stage (2 k-steps = 8 KB) into LDS buffer `buf` (0..2).
// Each wave DMAs its 2 KB quarter with two global_load_lds width-16 ops.
// ---------------------------------------------------------------------------
__device__ __forceinline__ void load_stage(const unsigned short* __restrict__ bp,
                                           char* smem, int gs, int buf,
                                           int wid, int lane) {
  const char* gsrc = (const char*)bp + gs * 8192 + wid * 2048 + lane * 16;
  char* ldst = smem + BBUF_OFF + buf * 8192 + wid * 2048;   // wave-uniform base
  __builtin_amdgcn_global_load_lds(
      (const __attribute__((address_space(1))) void*)gsrc,
      (__attribute__((address_space(3))) void*)ldst, 16, 0, 0);
  __builtin_amdgcn_global_load_lds(
      (const __attribute__((address_space(1))) void*)(gsrc + 1024),
      (__attribute__((address_space(3))) void*)(ldst + 1024), 16, 0, 0);
}

// ---------------------------------------------------------------------------
// Main fused kernel v8 = v5 (best measured: 157 us, no spills, 3 blocks/CU)
// + T1 XCD-chunked blockIdx swizzle. HW dispatches blockIdx round-robin over
// the 8 XCDs; remapping logical tile = (hw%8)*256 + hw/8 gives each XCD a
// contiguous 256-block range (~2 batch images: ~3MB x + 0.58MB bp fits the
// 4MB per-XCD L2). v5's FETCH=129MB included ~50MB of bp/x-halo L2-miss
// refetch; swizzle targets exactly that. 2048 % 8 == 0 -> bijective.
// Wave wid owns ONE row x 32 cols x ALL 64 oc; 4 A + 4 B ds_read_b128 per
// 2-substep stage; rotation-swizzled slab; 72 x 8KB counted-vmcnt(2)
// triple-buffered B pipeline; setprio around MFMA clusters.
// ---------------------------------------------------------------------------
__global__ __launch_bounds__(256, 3) void moe_conv_kernel(
    const float* __restrict__ x,
    const float* __restrict__ eb,
    const unsigned short* __restrict__ bp,
    const float* __restrict__ gate,
    float* __restrict__ out) {
  __shared__ __align__(16) char smem[SMEM_BYTES];
  unsigned short* bbufs = (unsigned short*)(smem + BBUF_OFF);
  float* ldsg = (float*)(smem + LDSG_OFF);   // [patch 4][e 8]

  const int tid = threadIdx.x;
  // T1: XCD-chunked swizzle (grid = 2048 = 8 * 256, bijective)
  const int bid0 = blockIdx.x;
  const int bid = (bid0 & 7) * 256 + (bid0 >> 3);
  const int wseg = bid & 3;          // 4 column segments of 32
  const int hq = (bid >> 2) & 31;
  const int b = bid >> 7;
  const int w0 = wseg * 32;
  const int wid = tid >> 6;
  const int lane = tid & 63;
  const int quad = lane >> 4;
  const int l15 = lane & 15;

  // kick off B stage 0 DMA immediately (overlaps slab staging)
  load_stage(bp, smem, 0, 0, wid, lane);

  // gates for this block's 4 patches
  if (tid < 32) {
    ldsg[tid] = gate[((b * 16 + (hq >> 1)) * 16 + wseg * 4 + (tid >> 3)) * 8 + (tid & 7)];
  }

  // --- stage x slab: rows hq*4-1 .. hq*4+4, cols w0-1 .. w0+32, all c ---
  // rotation swizzle: within-row byte = (cp*4 + ((srow&7)<<4)) & 127
  const int hbase = hq * 4 - 1;
  const int wbase = w0 - 1;
  for (int flat = tid; flat < 6 * 32 * COLS; flat += 256) {
    int col = flat % COLS;
    int t = flat / COLS;
    int cp = t & 31;                    // channel pair
    int r = t >> 5;                     // slab row 0..5
    int gh = hbase + r;
    int gw_ = wbase + col;
    float v0 = 0.f, v1 = 0.f;
    if (((unsigned)gh < 128u) && ((unsigned)gw_ < 128u)) {
      const float* px = x + (((b * NCH + cp * 2) * NHH + gh) * NWW + gw_);
      v0 = px[0];
      v1 = px[NHH * NWW];
    }
    unsigned int pk = (unsigned int)f2bf(v0) | ((unsigned int)f2bf(v1) << 16);
    int srow = r * COLS + col;
    int boff = ((cp * 4) + ((srow & 7) << 4)) & 127;
    *(unsigned int*)(smem + srow * 128 + boff) = pk;
  }

  // B stage 1 DMA before the slab barrier (barrier drains both)
  load_stage(bp, smem, 1, 1, wid, lane);
  __syncthreads();    // slab ready + B stages 0,1 landed (full drain, once)

  const v4f vzero = {0.f, 0.f, 0.f, 0.f};
  v4f oacc[2][4];
#pragma unroll
  for (int mt = 0; mt < 2; ++mt)
#pragma unroll
    for (int nt = 0; nt < 4; ++nt) oacc[mt][nt] = vzero;

  // wave/lane constants for A addressing
  const int q16 = quad * 16;
  const int lw  = l15 + 2 * wid;                 // for (srow&7) at read
  const int rowb = (wid * COLS + l15) * 128;     // byte base (kh=kw=0)

  for (int e = 0; e < 8; ++e) {
    v4f vacc[2][4];
#pragma unroll
    for (int mt = 0; mt < 2; ++mt)
#pragma unroll
      for (int nt = 0; nt < 4; ++nt) vacc[mt][nt] = vzero;

#pragma unroll
    for (int st = 0; st < 9; ++st) {
      const int gs = e * 9 + st;        // flat stage 0..71
      if (gs > 0) {
        asm volatile("s_waitcnt vmcnt(2)" ::: "memory");  // stage gs landed
        __builtin_amdgcn_s_barrier();                     // all waves agree
        __builtin_amdgcn_sched_barrier(0);
      }
      // prefetch stage gs+2 (clamped dummy at tail keeps vmcnt uniform);
      // target buffer (st+2)%3 == (gs-1)%3 was consumed before this barrier
      {
        int g2 = gs + 2;
        if (g2 > 71) g2 = 71;
        load_stage(bp, smem, g2, (gs + 2) % 3, wid, lane);
      }

      const unsigned short* bstage = bbufs + (st % 3) * 4096;
#pragma unroll
      for (int sub = 0; sub < 2; ++sub) {
        const int sl = st * 2 + sub;    // expert-local k-step 0..17
        const int kh = sl / 6;
        const int kw = (sl / 2) % 3;
        const int ch = sl & 1;
        v8s bf[4];
#pragma unroll
        for (int nt = 0; nt < 4; ++nt)
          bf[nt] = *(const v8s*)(bstage + (sub * 4 + nt) * 512 + lane * 8);
        // A byte address: srow = (wid+kh)*COLS + mt*16 + l15 + kw
        // swizzled channel offset = (q16 + ch*64 + ((srow&7)<<4)) & 127
        const int rot = ((lw + 2 * kh + kw) & 7) << 4;
        const int aoff = (q16 + ch * 64 + rot) & 127;
        const char* arow = smem + rowb + (kh * COLS + kw) * 128 + aoff;
        __builtin_amdgcn_s_setprio(1);
#pragma unroll
        for (int mt = 0; mt < 2; ++mt) {
          const v8s a = *(const v8s*)(smem + (rowb + (kh * COLS + kw) * 128 + aoff) + mt * 2048);
          (void)arow;
#pragma unroll
          for (int nt = 0; nt < 4; ++nt)
            vacc[mt][nt] = __builtin_amdgcn_mfma_f32_16x16x32_bf16(a, bf[nt], vacc[mt][nt], 0, 0, 0);
        }
        __builtin_amdgcn_s_setprio(0);
      }
    }

    // epilogue: bias + relu + gate, accumulate into oacc (wave-private)
    float bias[4];
#pragma unroll
    for (int nt = 0; nt < 4; ++nt) bias[nt] = eb[e * NOC + nt * 16 + l15];
#pragma unroll
    for (int mt = 0; mt < 2; ++mt) {
      float g = ldsg[(mt * 2 + (quad >> 1)) * 8 + e];
#pragma unroll
      for (int nt = 0; nt < 4; ++nt)
#pragma unroll
        for (int r = 0; r < 4; ++r) {
          float v = fmaxf(vacc[mt][nt][r] + bias[nt], 0.f);
          oacc[mt][nt][r] += v * g;
        }
    }
  }

  // ---- transpose through LDS (per-wave region) for full-line stores ----
  // D-frag mapping: m (pixel col) = mt*16 + quad*4 + r ; n (oc) = nt*16 + l15
  __syncthreads();                      // drains dummy prefetches + all reads
  float* tb = (float*)smem + wid * 2304;  // [oc:64][36] floats = 9216 B
#pragma unroll
  for (int mt = 0; mt < 2; ++mt)
#pragma unroll
    for (int nt = 0; nt < 4; ++nt)
      *(v4f*)(tb + (nt * 16 + l15) * 36 + mt * 16 + quad * 4) = oacc[mt][nt];
  // wave-private region: in-wave lgkmcnt ordering suffices, no barrier

  const int h = hq * 4 + wid;
  const int l7 = lane & 7;
  const int o8 = lane >> 3;
#pragma unroll
  for (int g4 = 0; g4 < 8; ++g4) {
    const int ocl = g4 * 8 + o8;                // 0..63
    const v4f vv = *(const v4f*)(tb + ocl * 36 + l7 * 4);
    float* dst = out + ((b * NOC + ocl) * NHH + h) * NWW + w0 + l7 * 4;
    *(v4f*)dst = vv;
  }
}

// ---------------------------------------------------------------------------
extern "C" void kernel_launch(void* const* d_in, const int* in_sizes, int n_in,
                              void* d_out, int out_size, void* d_ws, size_t ws_size,
                              hipStream_t stream) {
  const float* x  = (const float*)d_in[0];
  const float* ew = (const float*)d_in[1];
  const float* eb = (const float*)d_in[2];
  const float* gw = (const float*)d_in[3];
  const float* gb = (const float*)d_in[4];
  float* out = (float*)d_out;

  unsigned short* bp = (unsigned short*)d_ws;              // 294912 bf16 = 589824 B
  float* gate = (float*)((char*)d_ws + 589824);            // 4096*8 fp32 = 131072 B

  hipLaunchKernelGGL(pack_b_kernel, dim3(1152), dim3(256), 0, stream, ew, bp);
  hipLaunchKernelGGL(gate_kernel, dim3(256), dim3(512), 0, stream, x, gw, gb, gate);
  hipLaunchKernelGGL(moe_conv_kernel, dim3(2048), dim3(256), 0, stream, x, eb, bp, gate, out);
}